// Round 1
// baseline (659.468 us; speedup 1.0000x reference)
//
#include <hip/hip_runtime.h>

// Problem shape (from reference setup_inputs):
//   N=300000 source nodes, K=6 neighbors, F=64 features, N_up=75000 selections.
// pushed table: N x 65 floats (col 0 = pushed relu-weight sum, cols 1..64 = features)

#define KNB 6
#define FDIM 64
#define ROWW 65  // FDIM + 1

// One 64-lane "row" per source node; lane = feature index.
__global__ void push_scatter_kernel(const float* __restrict__ features,
                                    const float* __restrict__ weight,
                                    const float* __restrict__ nweights,
                                    const int*   __restrict__ nidx,
                                    float* __restrict__ pushed,
                                    int N) {
    const int rows_per_block = blockDim.x >> 6;
    const int i = blockIdx.x * rows_per_block + (threadIdx.x >> 6);
    const int f = threadIdx.x & 63;
    if (i >= N) return;

    float w = weight[i];
    w = w > 0.0f ? w : 0.0f;
    const float uf = features[(size_t)i * FDIM + f] * w;

    // Load the 6 neighbor (idx, weight) pairs once per lane (broadcast via L1).
    #pragma unroll
    for (int k = 0; k < KNB; ++k) {
        const int   idx = nidx[(size_t)i * KNB + k];
        const float nw  = nweights[(size_t)i * KNB + k];
        if (idx >= 0) {
            atomicAdd(&pushed[(size_t)idx * ROWW + 1 + f], nw * uf);
            if (f == 0) {
                atomicAdd(&pushed[(size_t)idx * ROWW], nw * w);
            }
        }
    }
}

// One 64-lane row per selection entry.
__global__ void gather_kernel(const float* __restrict__ pushed,
                              const int*   __restrict__ sel,
                              float* __restrict__ out,
                              int Nup) {
    const int rows_per_block = blockDim.x >> 6;
    const int u = blockIdx.x * rows_per_block + (threadIdx.x >> 6);
    const int f = threadIdx.x & 63;
    if (u >= Nup) return;

    const int s = sel[u];
    const float denom = pushed[(size_t)s * ROWW] + 0.001f;
    const float val   = pushed[(size_t)s * ROWW + 1 + f];
    out[(size_t)u * FDIM + f] = (denom == 0.0f) ? 0.0f : (val / denom);
}

extern "C" void kernel_launch(void* const* d_in, const int* in_sizes, int n_in,
                              void* d_out, int out_size, void* d_ws, size_t ws_size,
                              hipStream_t stream) {
    const float* features = (const float*)d_in[0];  // N*64
    const float* weight   = (const float*)d_in[1];  // N
    const float* nweights = (const float*)d_in[2];  // N*6
    const int*   nidx     = (const int*)d_in[3];    // N*6
    const int*   sel      = (const int*)d_in[4];    // N_up

    const int N   = in_sizes[1];
    const int Nup = in_sizes[4];

    float* pushed = (float*)d_ws;  // N * 65 floats

    // Zero the accumulation table (ws is re-poisoned to 0xAA before every call).
    hipMemsetAsync(pushed, 0, (size_t)N * ROWW * sizeof(float), stream);

    // Scatter: 4 source rows per 256-thread block.
    {
        const int rows_per_block = 4;
        const int blocks = (N + rows_per_block - 1) / rows_per_block;
        push_scatter_kernel<<<blocks, rows_per_block * 64, 0, stream>>>(
            features, weight, nweights, nidx, pushed, N);
    }

    // Gather + divide.
    {
        const int rows_per_block = 4;
        const int blocks = (Nup + rows_per_block - 1) / rows_per_block;
        gather_kernel<<<blocks, rows_per_block * 64, 0, stream>>>(
            pushed, sel, (float*)d_out, Nup);
    }
}

// Round 2
// 471.537 us; speedup vs baseline: 1.3986x; 1.3986x over previous
//
#include <hip/hip_runtime.h>

// Shape: N=300000 src nodes, K=6 neighbors, F=64 features, N_up=75000 selections.
// Strategy: invert the scatter-add into a per-destination gather.
//   1) count in-edges per destination          (1.8M int atomics)
//   2) allocate CSR slabs via one global cursor (per-wave prefix + 1 atomic/wave;
//      slab order is arbitrary — no global scan needed)
//   3) fill CSR with edge ids                  (1.8M int atomics + writes)
//   4) one 64-lane wave per sel entry walks its in-edges, accumulating
//      numerator (lane = feature) and denominator (lane-redundant), divides,
//      writes coalesced. No f32 atomics, no 78MB pushed table.

#define KNB 6
#define FDIM 64

__global__ void count_kernel(const int* __restrict__ nidx,
                             int* __restrict__ counts,
                             int E) {
    const int e = blockIdx.x * blockDim.x + threadIdx.x;
    if (e >= E) return;
    const int idx = nidx[e];
    if (idx >= 0) atomicAdd(&counts[idx], 1);
}

__global__ void alloc_kernel(const int* __restrict__ counts,
                             int* __restrict__ row_start,
                             int* __restrict__ cur,
                             int* __restrict__ cursor,
                             int N) {
    const int row  = blockIdx.x * blockDim.x + threadIdx.x;
    const int lane = threadIdx.x & 63;
    const int c = (row < N) ? counts[row] : 0;
    // wave-inclusive prefix sum of c
    int pre = c;
    #pragma unroll
    for (int d = 1; d < 64; d <<= 1) {
        int t = __shfl_up(pre, d);
        if (lane >= d) pre += t;
    }
    const int total = __shfl(pre, 63);
    int base = 0;
    if (lane == 63) base = atomicAdd(cursor, total);
    base = __shfl(base, 63);
    if (row < N) {
        const int start = base + pre - c;  // exclusive prefix
        row_start[row] = start;
        cur[row] = start;
    }
}

__global__ void fill_kernel(const int* __restrict__ nidx,
                            int* __restrict__ cur,
                            int* __restrict__ csr,
                            int E) {
    const int e = blockIdx.x * blockDim.x + threadIdx.x;
    if (e >= E) return;
    const int idx = nidx[e];
    if (idx >= 0) {
        const int p = atomicAdd(&cur[idx], 1);
        csr[p] = e;  // edge id = i*6 + k
    }
}

__global__ void gather_kernel(const float* __restrict__ features,
                              const float* __restrict__ weight,
                              const float* __restrict__ nweights,
                              const int*   __restrict__ sel,
                              const int*   __restrict__ counts,
                              const int*   __restrict__ row_start,
                              const int*   __restrict__ csr,
                              float* __restrict__ out,
                              int Nup) {
    const int rows_per_block = blockDim.x >> 6;
    const int u = blockIdx.x * rows_per_block + (threadIdx.x >> 6);
    const int f = threadIdx.x & 63;
    if (u >= Nup) return;

    const int s     = sel[u];
    const int start = row_start[s];
    const int end   = start + counts[s];

    float acc = 0.0f;    // numerator, lane f
    float dsum = 0.0f;   // denominator (same on every lane)
    for (int p = start; p < end; ++p) {
        const int eid = csr[p];        // wave-uniform
        const int i   = eid / KNB;
        const float nw = nweights[eid];
        float w = weight[i];
        w = w > 0.0f ? w : 0.0f;
        const float wn = nw * w;
        acc  += wn * features[(size_t)i * FDIM + f];
        dsum += wn;
    }
    const float d = dsum + 0.001f;
    out[(size_t)u * FDIM + f] = (d == 0.0f) ? 0.0f : (acc / d);
}

extern "C" void kernel_launch(void* const* d_in, const int* in_sizes, int n_in,
                              void* d_out, int out_size, void* d_ws, size_t ws_size,
                              hipStream_t stream) {
    const float* features = (const float*)d_in[0];  // N*64
    const float* weight   = (const float*)d_in[1];  // N
    const float* nweights = (const float*)d_in[2];  // N*6
    const int*   nidx     = (const int*)d_in[3];    // N*6
    const int*   sel      = (const int*)d_in[4];    // N_up

    const int N   = in_sizes[1];
    const int Nup = in_sizes[4];
    const int E   = N * KNB;

    // ws layout: counts[N] | cursor[1] | row_start[N] | cur[N] | csr[E]
    int* counts    = (int*)d_ws;
    int* cursor    = counts + N;
    int* row_start = cursor + 1;
    int* cur       = row_start + N;
    int* csr       = cur + N;

    // zero counts + cursor in one memset (ws is re-poisoned to 0xAA each call)
    hipMemsetAsync(counts, 0, (size_t)(N + 1) * sizeof(int), stream);

    const int T = 256;
    count_kernel<<<(E + T - 1) / T, T, 0, stream>>>(nidx, counts, E);
    alloc_kernel<<<(N + T - 1) / T, T, 0, stream>>>(counts, row_start, cur, cursor, N);
    fill_kernel <<<(E + T - 1) / T, T, 0, stream>>>(nidx, cur, csr, E);

    const int rows_per_block = 4;  // 256 threads = 4 waves
    gather_kernel<<<(Nup + rows_per_block - 1) / rows_per_block, rows_per_block * 64, 0, stream>>>(
        features, weight, nweights, sel, counts, row_start, csr, (float*)d_out, Nup);
}

// Round 3
// 197.725 us; speedup vs baseline: 3.3353x; 2.3848x over previous
//
#include <hip/hip_runtime.h>

// Shape: N=300000 src nodes, K=6 neighbors, F=64 features, N_up=75000 selections.
// Strategy: per-destination linked lists, built ONLY for selected destinations.
//   1) flag[sel[u]] = 1                        (75k plain writes; races benign)
//   2) build: edge e -> dest idx; if flagged: nxt[e]=head[idx] via atomicExch
//      (~0.4M atomics — 22% of edges; vs 3.6M in the CSR version)
//   3) gather: one 64-lane wave per sel entry walks its list (wave-uniform
//      pointer chase), accumulates num (lane=feature) + denom, divides, writes.
// No f32 atomics, no counts/alloc/fill passes, no 78MB pushed table.

#define KNB 6
#define FDIM 64

__global__ void flag_kernel(const int* __restrict__ sel,
                            int* __restrict__ flag,
                            int Nup) {
    const int u = blockIdx.x * blockDim.x + threadIdx.x;
    if (u < Nup) flag[sel[u]] = 1;
}

__global__ void build_kernel(const int* __restrict__ nidx,
                             const int* __restrict__ flag,
                             int* __restrict__ head,
                             int* __restrict__ nxt,
                             int E) {
    const int e = blockIdx.x * blockDim.x + threadIdx.x;
    if (e >= E) return;
    const int idx = nidx[e];
    if (idx >= 0 && flag[idx]) {
        // nxt[e] is only read by the NEXT kernel, so write order vs the
        // exchange doesn't matter; no intra-kernel readers.
        const int old = atomicExch(&head[idx], e);
        nxt[e] = old;
    }
}

__global__ void gather_kernel(const float* __restrict__ features,
                              const float* __restrict__ weight,
                              const float* __restrict__ nweights,
                              const int*   __restrict__ sel,
                              const int*   __restrict__ head,
                              const int*   __restrict__ nxt,
                              float* __restrict__ out,
                              int Nup) {
    const int rows_per_block = blockDim.x >> 6;
    const int u = blockIdx.x * rows_per_block + (threadIdx.x >> 6);
    const int f = threadIdx.x & 63;
    if (u >= Nup) return;

    const int s = sel[u];
    int e = head[s];

    float acc  = 0.0f;   // numerator, lane f
    float dsum = 0.0f;   // denominator (same on every lane)
    while (e >= 0) {
        const int i = e / KNB;                 // wave-uniform
        float w = weight[i];
        w = w > 0.0f ? w : 0.0f;
        const float wn = nweights[e] * w;
        acc  += wn * features[(size_t)i * FDIM + f];
        dsum += wn;
        e = nxt[e];
    }
    const float d = dsum + 0.001f;
    out[(size_t)u * FDIM + f] = (d == 0.0f) ? 0.0f : (acc / d);
}

extern "C" void kernel_launch(void* const* d_in, const int* in_sizes, int n_in,
                              void* d_out, int out_size, void* d_ws, size_t ws_size,
                              hipStream_t stream) {
    const float* features = (const float*)d_in[0];  // N*64
    const float* weight   = (const float*)d_in[1];  // N
    const float* nweights = (const float*)d_in[2];  // N*6
    const int*   nidx     = (const int*)d_in[3];    // N*6
    const int*   sel      = (const int*)d_in[4];    // N_up

    const int N   = in_sizes[1];
    const int Nup = in_sizes[4];
    const int E   = N * KNB;

    // ws layout: head[N] | flag[N] | nxt[E]
    int* head = (int*)d_ws;
    int* flag = head + N;
    int* nxt  = flag + N;

    // head := -1 (0xFF bytes), flag := 0. ws is re-poisoned each call.
    hipMemsetAsync(head, 0xFF, (size_t)N * sizeof(int), stream);
    hipMemsetAsync(flag, 0x00, (size_t)N * sizeof(int), stream);

    const int T = 256;
    flag_kernel <<<(Nup + T - 1) / T, T, 0, stream>>>(sel, flag, Nup);
    build_kernel<<<(E + T - 1) / T, T, 0, stream>>>(nidx, flag, head, nxt, E);

    const int rows_per_block = 4;  // 256 threads = 4 waves
    gather_kernel<<<(Nup + rows_per_block - 1) / rows_per_block, rows_per_block * 64, 0, stream>>>(
        features, weight, nweights, sel, head, nxt, (float*)d_out, Nup);
}